// Round 13
// baseline (157.310 us; speedup 1.0000x reference)
//
#include <hip/hip_runtime.h>

// Bilinear warp: out[b,c,i,j] = bilerp(trace[b,c], i + off0*256, j + off1*256)
// B=64, C=3, H=W=256. All fp32 in/out.
//
// v6 (resubmit after repeated infra failures): v4's row-pair fp16 gather (2
// gathers/pixel, 1 px/thread — best measured) + producer/consumer XCD
// affinity:
//   - repack block for batch b runs on XCD b>>3 (same XCD that gathers b)
//   - gather consumes batches in REVERSE order within each XCD, so the
//     most-recently-written batches (still resident in the 4 MB L2) are
//     read first.
// Hardware dispatch round-robins block g -> XCD g%8, so we encode the
// target XCD in the low 3 bits of blockIdx.

typedef _Float16 f16;
typedef f16 f16x8 __attribute__((ext_vector_type(8)));  // 16 B entry

constexpr int Hc = 256;
constexpr int Wc = 256;
constexpr int Cc = 3;
constexpr int Bc = 64;
constexpr int HWc = Hc * Wc;  // 65536
constexpr size_t PAIRED_BYTES = (size_t)Bc * HWc * sizeof(f16x8);  // 64 MiB

// ---------- Kernel 1: NCHW fp32 -> paired fp16 repack, XCD-affine ----------
// Entry (b,x,y) = {fp16 c0,c1,c2,pad of (x,y), fp16 c0,c1,c2,pad of (min(x+1,255),y)}
// Grid 4096 = 64 batches * 64 row-groups. Block g: xcd=g&7 handles batches
// [8*xcd, 8*xcd+8) in forward dispatch order.
__global__ __launch_bounds__(256) void repack_pair_f16_aff(
    const float* __restrict__ trace, f16x8* __restrict__ paired)
{
    const int g = blockIdx.x;            // [0, 4096)
    const int xcd = g & 7;
    const int slot = g >> 3;             // [0, 512) — increasing dispatch time per XCD
    const int b = (xcd << 3) | (slot >> 6);   // batches 8*xcd .. 8*xcd+7, forward
    const int xg = (slot & 63) << 2;     // row group base (0,4,...,252)
    const int y = threadIdx.x;           // column

    const float* tb = trace + (size_t)b * Cc * HWc;

    float rv[5][3];
    #pragma unroll
    for (int r = 0; r < 5; ++r) {
        const int xr = (xg + r < Hc) ? (xg + r) : (Hc - 1);
        const int base = (xr << 8) + y;
        #pragma unroll
        for (int c = 0; c < Cc; ++c) rv[r][c] = tb[c * HWc + base];
    }

    f16x8* dst = paired + (size_t)b * HWc + (xg << 8) + y;
    #pragma unroll
    for (int r = 0; r < 4; ++r) {
        f16x8 e;
        e[0] = (f16)rv[r][0];
        e[1] = (f16)rv[r][1];
        e[2] = (f16)rv[r][2];
        e[3] = (f16)0.0f;
        e[4] = (f16)rv[r + 1][0];
        e[5] = (f16)rv[r + 1][1];
        e[6] = (f16)rv[r + 1][2];
        e[7] = (f16)0.0f;
        dst[r << 8] = e;
    }
}

// ---------- Kernel 2: gather + bilerp, 1 px/thread, 2 gathers, ----------
// ---------- XCD-affine with REVERSED batch order per XCD          ----------
__global__ __launch_bounds__(256) void warp_gather_pair_f16_v6(
    const f16x8* __restrict__ paired,
    const float* __restrict__ offsets,
    float* __restrict__ out)
{
    // Grid 16384. Block g: xcd=g&7, slot=g>>3 in [0,2048). Each XCD covers
    // batches 8*xcd..8*xcd+7; consume them NEWEST-WRITTEN FIRST (reverse).
    const int g = blockIdx.x;
    const int xcd = g & 7;
    const int slot = g >> 3;             // [0, 2048)
    const int bslot = slot >> 8;         // [0, 8) batch slot (time order)
    const int b = (xcd << 3) | (7 - bslot);   // reversed: freshest L2 lines first
    const int pblk = slot & 255;         // 256 blocks per batch
    const int p = (pblk << 8) | threadIdx.x;

    const int i = p >> 8;
    const int j = p & (Wc - 1);

    const float* offb = offsets + (size_t)b * 2 * HWc;
    const float ox = offb[p] * 256.0f;
    const float oy = offb[HWc + p] * 256.0f;

    const float sx = fminf(fmaxf((float)i + ox, 0.0f), 255.0f);
    const float sy = fminf(fmaxf((float)j + oy, 0.0f), 255.0f);

    const float flx = floorf(sx);
    const float fly = floorf(sy);
    const int x0 = (int)flx;
    const int y0 = (int)fly;
    const int y1 = (int)ceilf(sy);
    const float fx = sx - flx;
    const float fy = sy - fly;

    const f16x8* tb = paired + (size_t)b * HWc + (x0 << 8);
    const f16x8 e0 = tb[y0];   // v00 (lo) + v10 (hi)
    const f16x8 e1 = tb[y1];   // v01 (lo) + v11 (hi)

    float* ob = out + (size_t)b * Cc * HWc;
    #pragma unroll
    for (int c = 0; c < Cc; ++c) {
        const float v00 = (float)e0[c];
        const float v10 = (float)e0[c + 4];
        const float v01 = (float)e1[c];
        const float v11 = (float)e1[c + 4];
        const float xu = v00 + (v10 - v00) * fx;
        const float xb = v01 + (v11 - v01) * fx;
        ob[c * HWc + p] = xu + (xb - xu) * fy;
    }
}

// ---------- Fallback (if workspace too small): fused fp32 kernel ----------
__global__ __launch_bounds__(256) void warp_bilinear_kernel(
    const float* __restrict__ trace,
    const float* __restrict__ offsets,
    float* __restrict__ out)
{
    const int idx = blockIdx.x * blockDim.x + threadIdx.x;
    const int b = idx >> 16;
    const int p = idx & (HWc - 1);
    const int i = p >> 8;
    const int j = p & (Wc - 1);

    const float* offb = offsets + (size_t)b * 2 * HWc;
    const float ox = offb[p] * 256.0f;
    const float oy = offb[HWc + p] * 256.0f;

    const float sx = fminf(fmaxf((float)i + ox, 0.0f), 255.0f);
    const float sy = fminf(fmaxf((float)j + oy, 0.0f), 255.0f);

    const float flx = floorf(sx);
    const float fly = floorf(sy);
    const int x0 = (int)flx;
    const int y0 = (int)fly;
    const int x1 = (int)ceilf(sx);
    const int y1 = (int)ceilf(sy);
    const float fx = sx - flx;
    const float fy = sy - fly;

    const int r0 = x0 << 8;
    const int r1 = x1 << 8;

    const float* tb = trace + (size_t)b * Cc * HWc;
    float* ob = out + (size_t)b * Cc * HWc;

    #pragma unroll
    for (int c = 0; c < Cc; ++c) {
        const float* tc = tb + c * HWc;
        const float v00 = tc[r0 + y0];
        const float v01 = tc[r0 + y1];
        const float v10 = tc[r1 + y0];
        const float v11 = tc[r1 + y1];
        const float xu = v00 + (v10 - v00) * fx;
        const float xb = v01 + (v11 - v01) * fx;
        ob[c * HWc + p] = xu + (xb - xu) * fy;
    }
}

extern "C" void kernel_launch(void* const* d_in, const int* in_sizes, int n_in,
                              void* d_out, int out_size, void* d_ws, size_t ws_size,
                              hipStream_t stream) {
    const float* trace = (const float*)d_in[0];
    const float* offsets = (const float*)d_in[1];
    float* out = (float*)d_out;

    const int total = Bc * HWc;  // 4,194,304 pixels

    if (ws_size >= PAIRED_BYTES) {
        f16x8* paired = (f16x8*)d_ws;
        repack_pair_f16_aff<<<Bc * (Hc / 4), 256, 0, stream>>>(trace, paired);       // 4096
        warp_gather_pair_f16_v6<<<total / 256, 256, 0, stream>>>(paired, offsets, out);  // 16384
    } else {
        warp_bilinear_kernel<<<total / 256, 256, 0, stream>>>(trace, offsets, out);
    }
}